// Round 1
// baseline (89.718 us; speedup 1.0000x reference)
//
#include <hip/hip_runtime.h>
#include <math.h>

// Shapes fixed by the reference: x [B=32, C=64, T=32, H=28, W=28] f32.
// Layout: idx = ((bc*T + t)*HW + hw). Recurrence runs over t (stride HW).
#define TT   32
#define HW   784            // 28*28
#define HW4  196            // HW / 4 (float4 granularity)
#define BC   (32 * 64)
#define NTHREADS (BC * HW4) // 401408 = 1568 * 256

__device__ __forceinline__ float spike_of(float u) {
    return u > 0.5f ? 1.0f : 0.0f;
}

__global__ __launch_bounds__(256) void lif_fwd_kernel(
        const float4* __restrict__ x,
        const float*  __restrict__ decay,
        float4*       __restrict__ out) {
    const int tid = blockIdx.x * blockDim.x + threadIdx.x;
    if (tid >= NTHREADS) return;

    const int bc  = tid / HW4;
    const int hw4 = tid - bc * HW4;
    const size_t base = (size_t)bc * (TT * HW4) + (size_t)hw4;

    // d = sigmoid(decay[0]); step-by-step f32 to match the reference's
    // per-op rounding (no fused/double-rounded shortcut).
    const float e = expf(-decay[0]);
    const float d = 1.0f / (1.0f + e);

    // t = 0: mem = x0, spike = (mem > 0.5)
    float4 mem = x[base];
    float4 s;
    s.x = spike_of(mem.x);
    s.y = spike_of(mem.y);
    s.z = spike_of(mem.z);
    s.w = spike_of(mem.w);
    out[base] = s;

    // t >= 1: mem = mem_old*d*(1-s_old) + x_t ; s = (mem > 0.5)
    // s_old is exactly 0 or 1, so select(0, mem*d) is bit-identical to the
    // reference's (mem*d)*(1-s). __fmul_rn/__fadd_rn forbid FMA contraction
    // so rounding matches a plain f32 mul-then-add chain.
    #pragma unroll
    for (int t = 1; t < TT; ++t) {
        const float4 xt = x[base + (size_t)t * HW4];
        mem.x = __fadd_rn(s.x != 0.0f ? 0.0f : __fmul_rn(mem.x, d), xt.x);
        mem.y = __fadd_rn(s.y != 0.0f ? 0.0f : __fmul_rn(mem.y, d), xt.y);
        mem.z = __fadd_rn(s.z != 0.0f ? 0.0f : __fmul_rn(mem.z, d), xt.z);
        mem.w = __fadd_rn(s.w != 0.0f ? 0.0f : __fmul_rn(mem.w, d), xt.w);
        s.x = spike_of(mem.x);
        s.y = spike_of(mem.y);
        s.z = spike_of(mem.z);
        s.w = spike_of(mem.w);
        out[base + (size_t)t * HW4] = s;
    }
}

extern "C" void kernel_launch(void* const* d_in, const int* in_sizes, int n_in,
                              void* d_out, int out_size, void* d_ws, size_t ws_size,
                              hipStream_t stream) {
    const float4* x     = (const float4*)d_in[0];
    const float*  decay = (const float*)d_in[1];
    float4*       out   = (float4*)d_out;

    const int block = 256;
    const int grid  = NTHREADS / block;  // 1568, exact
    lif_fwd_kernel<<<grid, block, 0, stream>>>(x, decay, out);
}

// Round 2
// 86.559 us; speedup vs baseline: 1.0365x; 1.0365x over previous
//
#include <hip/hip_runtime.h>
#include <math.h>

// Shapes fixed by the reference: x [B=32, C=64, T=32, H=28, W=28] f32.
// Layout: idx = ((bc*T + t)*HW + hw). Recurrence runs over t (stride HW).
#define TT   32
#define HW   784            // 28*28
#define HW4  196            // HW / 4 (float4 granularity)
#define BC   (32 * 64)
#define NTHREADS (BC * HW4) // 401408 = 6272 * 64

__device__ __forceinline__ float spike_of(float u) {
    return u > 0.5f ? 1.0f : 0.0f;
}

// block=64: 6272 blocks -> 24.5 blocks/CU (max 25, ~2% tail) vs block=256's
// 6.125/CU (max 7, ~14% tail). No LDS / no barriers, so tiny blocks are free.
__global__ __launch_bounds__(64) void lif_fwd_kernel(
        const float4* __restrict__ x,
        const float*  __restrict__ decay,
        float4*       __restrict__ out) {
    const int tid = blockIdx.x * blockDim.x + threadIdx.x;
    if (tid >= NTHREADS) return;

    const int bc  = tid / HW4;
    const int hw4 = tid - bc * HW4;
    const size_t base = (size_t)bc * (TT * HW4) + (size_t)hw4;

    // d = sigmoid(decay[0]); step-by-step f32 to match the reference's
    // per-op rounding (no fused/double-rounded shortcut).
    const float e = expf(-decay[0]);
    const float d = 1.0f / (1.0f + e);

    // t = 0: mem = x0, spike = (mem > 0.5)
    float4 mem = x[base];
    float4 s;
    s.x = spike_of(mem.x);
    s.y = spike_of(mem.y);
    s.z = spike_of(mem.z);
    s.w = spike_of(mem.w);
    out[base] = s;

    // t >= 1: mem = mem_old*d*(1-s_old) + x_t ; s = (mem > 0.5)
    // s_old is exactly 0 or 1, so select(0, mem*d) is bit-identical to the
    // reference's (mem*d)*(1-s). __fmul_rn/__fadd_rn forbid FMA contraction
    // so rounding matches a plain f32 mul-then-add chain.
    #pragma unroll
    for (int t = 1; t < TT; ++t) {
        const float4 xt = x[base + (size_t)t * HW4];
        mem.x = __fadd_rn(s.x != 0.0f ? 0.0f : __fmul_rn(mem.x, d), xt.x);
        mem.y = __fadd_rn(s.y != 0.0f ? 0.0f : __fmul_rn(mem.y, d), xt.y);
        mem.z = __fadd_rn(s.z != 0.0f ? 0.0f : __fmul_rn(mem.z, d), xt.z);
        mem.w = __fadd_rn(s.w != 0.0f ? 0.0f : __fmul_rn(mem.w, d), xt.w);
        s.x = spike_of(mem.x);
        s.y = spike_of(mem.y);
        s.z = spike_of(mem.z);
        s.w = spike_of(mem.w);
        out[base + (size_t)t * HW4] = s;
    }
}

extern "C" void kernel_launch(void* const* d_in, const int* in_sizes, int n_in,
                              void* d_out, int out_size, void* d_ws, size_t ws_size,
                              hipStream_t stream) {
    const float4* x     = (const float4*)d_in[0];
    const float*  decay = (const float*)d_in[1];
    float4*       out   = (float4*)d_out;

    const int block = 64;
    const int grid  = NTHREADS / block;  // 6272, exact
    lif_fwd_kernel<<<grid, block, 0, stream>>>(x, decay, out);
}